// Round 1
// 365.946 us; speedup vs baseline: 1.1086x; 1.1086x over previous
//
#include <hip/hip_runtime.h>
#include <hip/hip_bf16.h>
#include <stdint.h>

#define B_   4
#define N_   4096
#define HID_ 768
#define H_   12
#define DH_  64
#define NB_  266
#define NBP_ 288          // NB padded to multiple of 32
#define EPS_ 1e-4f
#define RATIO_ 0.06131393f  // 266^-0.5

typedef unsigned short u16;
typedef __attribute__((ext_vector_type(8))) short short8;
typedef __attribute__((ext_vector_type(4))) float floatx4;

__device__ __forceinline__ u16 f2b(float f) {
  __hip_bfloat16 h = __float2bfloat16(f);
  return *reinterpret_cast<u16*>(&h);
}
__device__ __forceinline__ float b2f(u16 u) {
  union { unsigned u; float f; } x; x.u = ((unsigned)u) << 16; return x.f;
}
__device__ __forceinline__ unsigned fmap(float x) {
  unsigned u = __float_as_uint(x);
  return (u & 0x80000000u) ? ~u : (u | 0x80000000u);
}
__device__ __forceinline__ float funmap(unsigned u) {
  unsigned b = (u & 0x80000000u) ? (u & 0x7FFFFFFFu) : ~u;
  return __uint_as_float(b);
}
__device__ __forceinline__ void gl16(const u16* g, u16* l) {
  __builtin_amdgcn_global_load_lds(
      (const __attribute__((address_space(1))) void*)g,
      (__attribute__((address_space(3))) void*)l, 16, 0, 0);
}

// ---------------- fused prep: converts + proj prep + mbuf init (1 launch) ----------------
// block ranges: [0,12288) hs | [12288,14016) W | [14016,14088) proj | 14088 mbuf
__global__ __launch_bounds__(256) void k_prep(
    const float4* __restrict__ hs, const float4* __restrict__ Wq,
    const float4* __restrict__ Wk, const float4* __restrict__ Wv,
    const float* __restrict__ proj,
    uint2* __restrict__ hsb, uint2* __restrict__ wb3, u16* __restrict__ projb,
    unsigned* __restrict__ mbuf) {
  int blk = blockIdx.x;
  const int t = threadIdx.x;
  if (blk < 12288) {
    int i = blk * 256 + t;
    float4 v = hs[i];
    union { u16 s[4]; uint2 u; } pk;
    pk.s[0] = f2b(v.x); pk.s[1] = f2b(v.y); pk.s[2] = f2b(v.z); pk.s[3] = f2b(v.w);
    hsb[i] = pk.u;
    return;
  }
  blk -= 12288;
  if (blk < 1728) {
    int i = blk * 256 + t;               // 0..442367, uniform sel per block
    int sel = i / 147456, j = i - sel * 147456;
    const float4* s = (sel == 0) ? Wq : (sel == 1) ? Wk : Wv;
    float4 v = s[j];
    union { u16 s4[4]; uint2 u; } pk;
    pk.s4[0] = f2b(v.x); pk.s4[1] = f2b(v.y); pk.s4[2] = f2b(v.z); pk.s4[3] = f2b(v.w);
    wb3[i] = pk.u;
    return;
  }
  blk -= 1728;
  if (blk < 72) {
    int i = blk * 256 + t;               // NBP_*DH_ = 18432 exact
    int j = i / DH_, d = i - j * DH_;
    float v = (j < NB_) ? proj[j * DH_ + d] * 0.35355339059327373f : 0.f;  // fold dn
    projb[i] = f2b(v);
    return;
  }
  blk -= 72;
  if (blk == 0 && t < B_ * H_) mbuf[t] = 0u;
}

// ---------------- QKV GEMM: BK=64 as two BK=32 panels; v written transposed ----------------
__global__ __launch_bounds__(256) void k_qkv(
    const u16* __restrict__ hsb, const u16* __restrict__ wb,
    const float* __restrict__ bq, const float* __restrict__ bk, const float* __restrict__ bv,
    u16* __restrict__ qb, u16* __restrict__ kb, u16* __restrict__ vT) {
  __shared__ u16 At[2 * 128 * 32];   // [panel][row][32]
  __shared__ u16 Bt[2 * 128 * 32];
  const int m0 = blockIdx.x * 128;
  const int bn = blockIdx.y;
  const int sel = bn / 6;                  // 0:q 1:k 2:v
  const int or0 = (bn % 6) * 128;
  const u16* W = wb + (size_t)sel * HID_ * HID_;
  const int t = threadIdx.x, lane = t & 63, wv = t >> 6;
  const int wr = (wv >> 1) * 64, wc = (wv & 1) * 64;
  const int lm = lane & 15, lq = lane >> 4;
  const int srow = wv * 32 + (lane >> 2);
  const int scol = (lane & 3) * 8;
  const u16* gA = hsb + (size_t)(m0 + srow) * HID_ + scol;
  const u16* gB = W + (size_t)(or0 + srow) * HID_ + scol;
  u16* lA = At + wv * 1024;
  u16* lB = Bt + wv * 1024;
  floatx4 acc[4][4];
#pragma unroll
  for (int i = 0; i < 4; i++)
#pragma unroll
    for (int j = 0; j < 4; j++) acc[i][j] = (floatx4){0.f, 0.f, 0.f, 0.f};

  for (int k0 = 0; k0 < HID_; k0 += 64) {
    __syncthreads();
#pragma unroll
    for (int p = 0; p < 2; p++) {
#pragma unroll
      for (int i = 0; i < 2; i++) {
        gl16(gA + k0 + p * 32 + i * 16 * HID_, lA + p * 4096 + i * 512);
        gl16(gB + k0 + p * 32 + i * 16 * HID_, lB + p * 4096 + i * 512);
      }
    }
    __syncthreads();
#pragma unroll
    for (int p = 0; p < 2; p++) {
      short8 af[4], bfr[4];
#pragma unroll
      for (int mt = 0; mt < 4; mt++) af[mt] = *(const short8*)&At[p * 4096 + (wr + mt * 16 + lm) * 32 + lq * 8];
#pragma unroll
      for (int nt = 0; nt < 4; nt++) bfr[nt] = *(const short8*)&Bt[p * 4096 + (wc + nt * 16 + lm) * 32 + lq * 8];
#pragma unroll
      for (int mt = 0; mt < 4; mt++)
#pragma unroll
        for (int nt = 0; nt < 4; nt++)
          acc[mt][nt] = __builtin_amdgcn_mfma_f32_16x16x32_bf16(af[mt], bfr[nt], acc[mt][nt], 0, 0, 0);
    }
  }
  if (sel < 2) {
    const float* bias = (sel == 0) ? bq : bk;
    u16* dst = (sel == 0) ? qb : kb;
#pragma unroll
    for (int mt = 0; mt < 4; mt++) {
#pragma unroll
      for (int nt = 0; nt < 4; nt++) {
        int lc = or0 + wc + nt * 16 + lm;
        float bb = bias[lc];
#pragma unroll
        for (int r = 0; r < 4; r++) {
          int row = m0 + wr + mt * 16 + lq * 4 + r;
          dst[(size_t)row * HID_ + lc] = f2b(acc[mt][nt][r] + bb);
        }
      }
    }
  } else {
#pragma unroll
    for (int mt = 0; mt < 4; mt++) {
#pragma unroll
      for (int nt = 0; nt < 4; nt++) {
        int lc = or0 + wc + nt * 16 + lm;
        int hh = lc >> 6, dv = lc & 63;
        float bb = bv[lc];
        int rowbase = m0 + wr + mt * 16 + lq * 4;
        int b = rowbase >> 12, n = rowbase & 4095;
        union { u16 s[4]; uint2 u; } pk;
#pragma unroll
        for (int r = 0; r < 4; r++) pk.s[r] = f2b(acc[mt][nt][r] + bb);
        *(uint2*)(vT + ((size_t)(b * H_ + hh) * DH_ + dv) * N_ + n) = pk.u;
      }
    }
  }
}

// ---------------- global max of k features per (b,h) + diag(k) precompute ----------------
__global__ __launch_bounds__(256) void k_kmax3(
    const u16* __restrict__ kb, const u16* __restrict__ projb,
    unsigned* __restrict__ mbuf, float* __restrict__ diagk) {
  const int bh = blockIdx.y, b = bh / H_, h = bh - b * H_;
  const int n0 = blockIdx.x * 256;
  const int t = threadIdx.x, lane = t & 63, wv = t >> 6;
  const int lm = lane & 15, lq = lane >> 4;
  const u16* kbase = kb + (size_t)(b * N_ + n0 + wv * 64) * HID_ + h * DH_;
  short8 af0[4], af1[4];
#pragma unroll
  for (int mt = 0; mt < 4; mt++) {
    const u16* p = kbase + (size_t)(mt * 16 + lm) * HID_ + lq * 8;
    af0[mt] = *(const short8*)p;
    af1[mt] = *(const short8*)(p + 32);
  }
  // diag(k) = 0.0625 * sum_d k^2 per row — bit-identical to old in-loop computation
#pragma unroll
  for (int mt = 0; mt < 4; mt++) {
    float rs = 0.f;
#pragma unroll
    for (int i = 0; i < 8; i++) { float f = b2f(((const u16*)&af0[mt])[i]); rs += f * f; }
#pragma unroll
    for (int i = 0; i < 8; i++) { float f = b2f(((const u16*)&af1[mt])[i]); rs += f * f; }
    rs += __shfl_xor(rs, 16);
    rs += __shfl_xor(rs, 32);
    if (lq == 0) diagk[(size_t)bh * N_ + n0 + wv * 64 + mt * 16 + lm] = 0.0625f * rs;
  }
  float mx = -3e38f;
  for (int ct = 0; ct < 17; ct++) {
    const u16* pp = projb + (ct * 16 + lm) * DH_ + lq * 8;
    short8 bf0 = *(const short8*)pp;
    short8 bf1 = *(const short8*)(pp + 32);
    bool valid = (ct < 16) || (lm < 10);
#pragma unroll
    for (int mt = 0; mt < 4; mt++) {
      floatx4 a = __builtin_amdgcn_mfma_f32_16x16x32_bf16(af0[mt], bf0, (floatx4){0.f,0.f,0.f,0.f}, 0, 0, 0);
      a = __builtin_amdgcn_mfma_f32_16x16x32_bf16(af1[mt], bf1, a, 0, 0, 0);
      if (valid) {
#pragma unroll
        for (int r = 0; r < 4; r++) mx = fmaxf(mx, a[r]);
      }
    }
  }
#pragma unroll
  for (int o = 1; o < 64; o <<= 1) mx = fmaxf(mx, __shfl_xor(mx, o));
  if (lane == 0) atomicMax(&mbuf[bh], fmap(mx));
}

// ---------------- j-owned k-features + ctx reduction: no atomics, reg accumulator ----------------
// grid: 432 blocks = 48 bh x 9 j-blocks of 32; XCD-swizzled so same-bh blocks share an XCD L2.
__global__ __launch_bounds__(256) void k_ctx4(
    const u16* __restrict__ kb, const u16* __restrict__ vT, const u16* __restrict__ projb,
    const unsigned* __restrict__ mbuf, const float* __restrict__ diagk,
    float* __restrict__ ksum, u16* __restrict__ ctxb) {
  __shared__ u16 kpl[32 * 72];       // [j in tile][n 0..63, pad to 72]
  __shared__ float kred[4][2][16];
  const int orig = blockIdx.x;
  const int lg = (orig & 7) * 54 + (orig >> 3);   // bijective XCD swizzle (432 = 8*54)
  const int bh = lg / 9, jb = lg - bh * 9;
  const int j0 = jb * 32;
  const int b = bh / H_, h = bh - b * H_;
  const int t = threadIdx.x, lane = t & 63, wv = t >> 6;
  const int lm = lane & 15, lq = lane >> 4;
  const float m = funmap(mbuf[bh]);
  const bool vj0 = (j0 + lm) < NB_;
  const bool vj1 = (j0 + 16 + lm) < NB_;
  // proj fragments for this block's 32 j-rows: hoisted for the whole kernel
  short8 bp00, bp01, bp10, bp11;
  {
    const u16* pp = projb + (j0 + lm) * DH_ + lq * 8;
    bp00 = *(const short8*)pp;
    bp01 = *(const short8*)(pp + 32);
    pp += 16 * DH_;
    bp10 = *(const short8*)pp;
    bp11 = *(const short8*)(pp + 32);
  }
  const u16* kbB = kb + (size_t)(b * N_) * HID_ + h * DH_;
  const u16* vTb = vT + ((size_t)bh * DH_ + wv * 16 + lm) * N_;
  const float* dgB = diagk + (size_t)bh * N_;
  floatx4 acc0 = (floatx4){0.f,0.f,0.f,0.f}, acc1 = (floatx4){0.f,0.f,0.f,0.f};
  float kacc0 = 0.f, kacc1 = 0.f;
  // preload tile 0 (k rows + diag)
  const u16* kr0 = kbB + (size_t)(wv * 16 + lm) * HID_ + lq * 8;
  short8 af0 = *(const short8*)kr0;
  short8 af1 = *(const short8*)(kr0 + 32);
  floatx4 dg4 = *(const floatx4*)(dgB + wv * 16 + lq * 4);

  for (int n64 = 0; n64 < N_; n64 += 64) {
    __syncthreads();
    // issue next-tile k/diag prefetch + this-tile v loads (all independent of phase A/B compute)
    const int nn = (n64 + 64 < N_) ? n64 + 64 : 0;
    const u16* krn = kbB + (size_t)(nn + wv * 16 + lm) * HID_ + lq * 8;
    short8 nf0 = *(const short8*)krn;
    short8 nf1 = *(const short8*)(krn + 32);
    floatx4 nd = *(const floatx4*)(dgB + nn + wv * 16 + lq * 4);
    short8 av0 = *(const short8*)(vTb + n64 + lq * 8);
    short8 av1 = *(const short8*)(vTb + n64 + 32 + lq * 8);
    // ---- phase A: features for this wave's 16 n-rows x 32 j ----
    {
      floatx4 a = __builtin_amdgcn_mfma_f32_16x16x32_bf16(af0, bp00, (floatx4){0.f,0.f,0.f,0.f}, 0, 0, 0);
      a = __builtin_amdgcn_mfma_f32_16x16x32_bf16(af1, bp01, a, 0, 0, 0);
      union { u16 s[4]; uint2 u; } pk;
      float kss = 0.f;
#pragma unroll
      for (int r = 0; r < 4; r++) {
        float val = vj0 ? RATIO_ * (__expf(a[r] - dg4[r] - m) + EPS_) : 0.f;
        kss += val;
        pk.s[r] = f2b(val);
      }
      kacc0 += kss;
      *(uint2*)&kpl[lm * 72 + wv * 16 + lq * 4] = pk.u;
      a = __builtin_amdgcn_mfma_f32_16x16x32_bf16(af0, bp10, (floatx4){0.f,0.f,0.f,0.f}, 0, 0, 0);
      a = __builtin_amdgcn_mfma_f32_16x16x32_bf16(af1, bp11, a, 0, 0, 0);
      kss = 0.f;
#pragma unroll
      for (int r = 0; r < 4; r++) {
        float val = vj1 ? RATIO_ * (__expf(a[r] - dg4[r] - m) + EPS_) : 0.f;
        kss += val;
        pk.s[r] = f2b(val);
      }
      kacc1 += kss;
      *(uint2*)&kpl[(16 + lm) * 72 + wv * 16 + lq * 4] = pk.u;
    }
    __syncthreads();
    // ---- phase B: ctx MFMA, wave owns d-rows wv*16..wv*16+15 ----
    {
      short8 bf = *(const short8*)&kpl[lm * 72 + lq * 8];
      acc0 = __builtin_amdgcn_mfma_f32_16x16x32_bf16(av0, bf, acc0, 0, 0, 0);
      bf = *(const short8*)&kpl[(16 + lm) * 72 + lq * 8];
      acc1 = __builtin_amdgcn_mfma_f32_16x16x32_bf16(av0, bf, acc1, 0, 0, 0);
      bf = *(const short8*)&kpl[lm * 72 + 32 + lq * 8];
      acc0 = __builtin_amdgcn_mfma_f32_16x16x32_bf16(av1, bf, acc0, 0, 0, 0);
      bf = *(const short8*)&kpl[(16 + lm) * 72 + 32 + lq * 8];
      acc1 = __builtin_amdgcn_mfma_f32_16x16x32_bf16(av1, bf, acc1, 0, 0, 0);
    }
    af0 = nf0; af1 = nf1; dg4 = nd;
  }
  // ---- ksum: cross-lq shuffle + cross-wave LDS reduce, single plain store ----
  {
    float v0 = kacc0; v0 += __shfl_xor(v0, 16); v0 += __shfl_xor(v0, 32);
    float v1 = kacc1; v1 += __shfl_xor(v1, 16); v1 += __shfl_xor(v1, 32);
    if (lq == 0) { kred[wv][0][lm] = v0; kred[wv][1][lm] = v1; }
  }
  __syncthreads();
  if (t < 32) {
    int jh = t >> 4, l = t & 15;
    ksum[bh * NBP_ + j0 + t] =
        kred[0][jh][l] + kred[1][jh][l] + kred[2][jh][l] + kred[3][jh][l];
  }
  // ---- ctx write: each block owns [64 d][32 j] exclusively — plain bf16 stores ----
  {
    u16* cb = ctxb + ((size_t)bh * DH_ + wv * 16 + lq * 4) * NBP_ + j0 + lm;
#pragma unroll
    for (int r = 0; r < 4; r++) {
      cb[(size_t)r * NBP_] = f2b(acc0[r]);
      cb[(size_t)r * NBP_ + 16] = f2b(acc1[r]);
    }
  }
}

// ---------------- fused q-features + out GEMM (two-pass, low VGPR) ----------------
__global__ __launch_bounds__(256) void k_out3(
    const u16* __restrict__ qb, const u16* __restrict__ projb,
    const u16* __restrict__ ctxb, const float* __restrict__ ksum,
    float* __restrict__ outp) {
  __shared__ u16 qpl[4][16][296];   // per-wave private 16x288 (+8 pad)
  const int bh = blockIdx.y, b = bh / H_, h = bh - b * H_;
  const int n0 = blockIdx.x * 256;
  const int t = threadIdx.x, lane = t & 63, wv = t >> 6;
  const int lm = lane & 15, lq = lane >> 4;
  const u16* qbase = qb + (size_t)(b * N_ + n0 + wv * 64) * HID_ + h * DH_;
  const u16* cb = ctxb + (size_t)bh * DH_ * NBP_;
  const float* ksb = ksum + bh * NBP_;
  float ksv[17];
#pragma unroll
  for (int ct = 0; ct < 17; ct++) ksv[ct] = ksb[ct * 16 + lm];

  for (int mt = 0; mt < 4; mt++) {
    const u16* prow = qbase + (size_t)(mt * 16 + lm) * HID_ + lq * 8;
    short8 af0 = *(const short8*)prow;
    short8 af1 = *(const short8*)(prow + 32);
    float rs = 0.f;
#pragma unroll
    for (int i = 0; i < 8; i++) { float f = b2f(((const u16*)&af0)[i]); rs += f * f; }
#pragma unroll
    for (int i = 0; i < 8; i++) { float f = b2f(((const u16*)&af1)[i]); rs += f * f; }
    rs += __shfl_xor(rs, 16);
    rs += __shfl_xor(rs, 32);
    float dg[4];
#pragma unroll
    for (int r = 0; r < 4; r++) dg[r] = 0.0625f * __shfl(rs, lq * 4 + r);

    // pass 1: row max only (no dd storage)
    float rm[4] = {-3e38f, -3e38f, -3e38f, -3e38f};
#pragma unroll
    for (int ct = 0; ct < 17; ct++) {
      const u16* pp = projb + (ct * 16 + lm) * DH_ + lq * 8;
      short8 bf0 = *(const short8*)pp;
      short8 bf1 = *(const short8*)(pp + 32);
      floatx4 a = __builtin_amdgcn_mfma_f32_16x16x32_bf16(af0, bf0, (floatx4){0.f,0.f,0.f,0.f}, 0, 0, 0);
      a = __builtin_amdgcn_mfma_f32_16x16x32_bf16(af1, bf1, a, 0, 0, 0);
      if ((ct < 16) || (lm < 10)) {
#pragma unroll
        for (int r = 0; r < 4; r++) rm[r] = fmaxf(rm[r], a[r]);
      }
    }
#pragma unroll
    for (int o = 1; o < 16; o <<= 1) {
#pragma unroll
      for (int r = 0; r < 4; r++) rm[r] = fmaxf(rm[r], __shfl_xor(rm[r], o));
    }
    // pass 2: recompute dd, exp, qp -> LDS, d partial
    float dpart[4] = {0.f, 0.f, 0.f, 0.f};
#pragma unroll
    for (int ct = 0; ct < 18; ct++) {
      floatx4 a;
      if (ct < 17) {
        const u16* pp = projb + (ct * 16 + lm) * DH_ + lq * 8;
        short8 bf0 = *(const short8*)pp;
        short8 bf1 = *(const short8*)(pp + 32);
        a = __builtin_amdgcn_mfma_f32_16x16x32_bf16(af0, bf0, (floatx4){0.f,0.f,0.f,0.f}, 0, 0, 0);
        a = __builtin_amdgcn_mfma_f32_16x16x32_bf16(af1, bf1, a, 0, 0, 0);
      } else {
        a = (floatx4){0.f, 0.f, 0.f, 0.f};
      }
      bool valid = (ct < 16) || (ct == 16 && lm < 10);
      float kv = (ct < 17) ? ksv[ct] : 0.f;
#pragma unroll
      for (int r = 0; r < 4; r++) {
        float qpv = valid ? RATIO_ * (__expf(a[r] - dg[r] - rm[r]) + EPS_) : 0.f;
        dpart[r] += qpv * kv;
        qpl[wv][lq * 4 + r][ct * 16 + lm] = f2b(qpv);
      }
    }
#pragma unroll
    for (int o = 1; o < 16; o <<= 1) {
#pragma unroll
      for (int r = 0; r < 4; r++) dpart[r] += __shfl_xor(dpart[r], o);
    }
    float dinv[4];
#pragma unroll
    for (int r = 0; r < 4; r++) dinv[r] = 1.f / dpart[r];

    floatx4 ao[4];
#pragma unroll
    for (int dt = 0; dt < 4; dt++) ao[dt] = (floatx4){0.f, 0.f, 0.f, 0.f};
#pragma unroll
    for (int ks9 = 0; ks9 < 9; ks9++) {
      short8 aq = *(const short8*)&qpl[wv][lm][ks9 * 32 + lq * 8];
#pragma unroll
      for (int dt = 0; dt < 4; dt++) {
        short8 bc = *(const short8*)(cb + (size_t)(dt * 16 + lm) * NBP_ + ks9 * 32 + lq * 8);
        ao[dt] = __builtin_amdgcn_mfma_f32_16x16x32_bf16(aq, bc, ao[dt], 0, 0, 0);
      }
    }
#pragma unroll
    for (int dt = 0; dt < 4; dt++) {
#pragma unroll
      for (int r = 0; r < 4; r++) {
        int n = n0 + wv * 64 + mt * 16 + lq * 4 + r;
        outp[((size_t)(b * N_ + n)) * HID_ + h * DH_ + dt * 16 + lm] = ao[dt][r] * dinv[r];
      }
    }
  }
}

extern "C" void kernel_launch(void* const* d_in, const int* in_sizes, int n_in,
                              void* d_out, int out_size, void* d_ws, size_t ws_size,
                              hipStream_t stream) {
  (void)in_sizes; (void)n_in; (void)out_size; (void)ws_size;
  const float* hs   = (const float*)d_in[0];
  const float* Wq   = (const float*)d_in[1];
  const float* bq   = (const float*)d_in[2];
  const float* Wk   = (const float*)d_in[3];
  const float* bk   = (const float*)d_in[4];
  const float* Wv   = (const float*)d_in[5];
  const float* bv   = (const float*)d_in[6];
  const float* proj = (const float*)d_in[7];

  char* w = (char*)d_ws;
  u16* hsb   = (u16*)w;  w += (size_t)16384 * 768 * 2;
  u16* wb3   = (u16*)w;  w += (size_t)3 * 768 * 768 * 2;
  u16* projb = (u16*)w;  w += (size_t)NBP_ * 64 * 2;
  u16* qb    = (u16*)w;  w += (size_t)16384 * 768 * 2;
  u16* kb    = (u16*)w;  w += (size_t)16384 * 768 * 2;
  u16* vT    = (u16*)w;  w += (size_t)48 * DH_ * N_ * 2;   // [bh][dv][n]
  float* ksum  = (float*)w; w += (size_t)48 * NBP_ * 4;
  float* diagk = (float*)w; w += (size_t)48 * N_ * 4;      // [bh][n] = 0.0625*sum k^2
  u16* ctxTb = (u16*)w;  w += (size_t)48 * DH_ * NBP_ * 2;
  unsigned* mbuf = (unsigned*)w;

  hipLaunchKernelGGL(k_prep, dim3(14089), dim3(256), 0, stream,
                     (const float4*)hs, (const float4*)Wq, (const float4*)Wk, (const float4*)Wv,
                     proj, (uint2*)hsb, (uint2*)wb3, projb, mbuf);
  hipLaunchKernelGGL(k_qkv, dim3(128, 18), dim3(256), 0, stream, hsb, wb3, bq, bk, bv, qb, kb, vT);
  hipLaunchKernelGGL(k_kmax3, dim3(16, 48), dim3(256), 0, stream, kb, projb, mbuf, diagk);
  hipLaunchKernelGGL(k_ctx4, dim3(432), dim3(256), 0, stream, kb, vT, projb, mbuf, diagk, ksum, ctxTb);
  hipLaunchKernelGGL(k_out3, dim3(16, 48), dim3(256), 0, stream, qb, projb, ctxTb, ksum, (float*)d_out);
}

// Round 2
// 364.370 us; speedup vs baseline: 1.1134x; 1.0043x over previous
//
#include <hip/hip_runtime.h>
#include <hip/hip_bf16.h>
#include <stdint.h>

#define B_   4
#define N_   4096
#define HID_ 768
#define H_   12
#define DH_  64
#define NB_  266
#define NBP_ 288          // NB padded to multiple of 32
#define EPS_ 1e-4f
#define RATIO_ 0.06131393f  // 266^-0.5

typedef unsigned short u16;
typedef __attribute__((ext_vector_type(8))) short short8;
typedef __attribute__((ext_vector_type(4))) float floatx4;

__device__ __forceinline__ u16 f2b(float f) {
  __hip_bfloat16 h = __float2bfloat16(f);
  return *reinterpret_cast<u16*>(&h);
}
__device__ __forceinline__ float b2f(u16 u) {
  union { unsigned u; float f; } x; x.u = ((unsigned)u) << 16; return x.f;
}
__device__ __forceinline__ unsigned fmap(float x) {
  unsigned u = __float_as_uint(x);
  return (u & 0x80000000u) ? ~u : (u | 0x80000000u);
}
__device__ __forceinline__ float funmap(unsigned u) {
  unsigned b = (u & 0x80000000u) ? (u & 0x7FFFFFFFu) : ~u;
  return __uint_as_float(b);
}
__device__ __forceinline__ void gl16(const u16* g, u16* l) {
  __builtin_amdgcn_global_load_lds(
      (const __attribute__((address_space(1))) void*)g,
      (__attribute__((address_space(3))) void*)l, 16, 0, 0);
}

// ---------------- fused prep: converts + proj prep + mbuf init (1 launch) ----------------
// block ranges: [0,12288) hs | [12288,14016) W | [14016,14088) proj | 14088 mbuf
__global__ __launch_bounds__(256) void k_prep(
    const float4* __restrict__ hs, const float4* __restrict__ Wq,
    const float4* __restrict__ Wk, const float4* __restrict__ Wv,
    const float* __restrict__ proj,
    uint2* __restrict__ hsb, uint2* __restrict__ wb3, u16* __restrict__ projb,
    unsigned* __restrict__ mbuf) {
  int blk = blockIdx.x;
  const int t = threadIdx.x;
  if (blk < 12288) {
    int i = blk * 256 + t;
    float4 v = hs[i];
    union { u16 s[4]; uint2 u; } pk;
    pk.s[0] = f2b(v.x); pk.s[1] = f2b(v.y); pk.s[2] = f2b(v.z); pk.s[3] = f2b(v.w);
    hsb[i] = pk.u;
    return;
  }
  blk -= 12288;
  if (blk < 1728) {
    int i = blk * 256 + t;               // 0..442367, uniform sel per block
    int sel = i / 147456, j = i - sel * 147456;
    const float4* s = (sel == 0) ? Wq : (sel == 1) ? Wk : Wv;
    float4 v = s[j];
    union { u16 s4[4]; uint2 u; } pk;
    pk.s4[0] = f2b(v.x); pk.s4[1] = f2b(v.y); pk.s4[2] = f2b(v.z); pk.s4[3] = f2b(v.w);
    wb3[i] = pk.u;
    return;
  }
  blk -= 1728;
  if (blk < 72) {
    int i = blk * 256 + t;               // NBP_*DH_ = 18432 exact
    int j = i / DH_, d = i - j * DH_;
    float v = (j < NB_) ? proj[j * DH_ + d] * 0.35355339059327373f : 0.f;  // fold dn
    projb[i] = f2b(v);
    return;
  }
  blk -= 72;
  if (blk == 0 && t < B_ * H_) mbuf[t] = 0u;
}

// ---------------- QKV GEMM v2: 256x256 tile, BK=32, 3-buf counted-vmcnt pipeline ----------------
// 8 waves (2Mx4N), wave owns 128x64. LDS 96KB = 3 x (A 256x32 | B 256x32) bf16.
// Staging 2 K-tiles ahead via global_load_lds; s_waitcnt vmcnt(4) per tile (never 0 in loop).
// Bank-conflict fix: linear LDS + pre-swizzled global source col (slot ^ ((row>>1)&3)),
// reads apply the same XOR -> each 16-lane quarter covers all bank-quads 2x (free).
__global__ __launch_bounds__(512, 2) void k_qkv2(
    const u16* __restrict__ hsb, const u16* __restrict__ wb,
    const float* __restrict__ bq, const float* __restrict__ bk, const float* __restrict__ bv,
    u16* __restrict__ qb, u16* __restrict__ kb, u16* __restrict__ vT) {
  __shared__ u16 lds[3 * 16384];   // 96 KiB
  const int orig = blockIdx.x;
  const int lg = (orig & 7) * 72 + (orig >> 3);   // 576 = 8*72, bijective XCD swizzle
  const int tm = lg / 9, tn = lg - tm * 9;
  const int m0 = tm * 256;
  const int c0 = tn * 256;
  const int sel = c0 / 768;                       // 0:q 1:k 2:v (256 | 768 -> no straddle)
  const int or0 = c0 - sel * 768;
  const u16* W = wb + (size_t)sel * HID_ * HID_;
  const int t = threadIdx.x, lane = t & 63, wv = t >> 6;
  const int lm = lane & 15, lq = lane >> 4;
  const int wvm = wv >> 2, wvn = wv & 3;
  // staging: thread t loads global (row = t>>2 [+128], col8 = (t&3)^((t>>3)&3)), lands at LDS slot t&3
  const int srow = t >> 2;
  const int scol = ((t & 3) ^ ((t >> 3) & 3)) * 8;
  const u16* gA0 = hsb + (size_t)(m0 + srow) * HID_ + scol;
  const u16* gB0 = W + (size_t)(or0 + srow) * HID_ + scol;
  u16* lb = lds + wv * 512;                       // wave-uniform staging base (u16 units)
  // fragment read offsets (u16 units); swizzled slot gives lane its k-chunk lq*8
  const int slotc = (lq ^ ((lm >> 1) & 3)) * 8;
  const int aoff = (wvm * 128 + lm) * 32 + slotc;
  const int boff = 8192 + (wvn * 64 + lm) * 32 + slotc;

  floatx4 acc[8][4];
#pragma unroll
  for (int mt = 0; mt < 8; mt++)
#pragma unroll
    for (int nt = 0; nt < 4; nt++) acc[mt][nt] = (floatx4){0.f, 0.f, 0.f, 0.f};

#define STAGE_QKV(kt)                                            \
  {                                                              \
    const int k0_ = (kt) * 32;                                   \
    u16* l_ = lb + ((kt) % 3) * 16384;                           \
    gl16(gA0 + k0_, l_);                                         \
    gl16(gA0 + 128 * HID_ + k0_, l_ + 4096);                     \
    gl16(gB0 + k0_, l_ + 8192);                                  \
    gl16(gB0 + 128 * HID_ + k0_, l_ + 12288);                    \
  }

  STAGE_QKV(0);
  STAGE_QKV(1);
  asm volatile("s_waitcnt vmcnt(4)" ::: "memory");   // tile 0 staged
  __builtin_amdgcn_s_barrier();

  for (int kt = 0; kt < 24; ++kt) {
    if (kt + 2 < 24) STAGE_QKV(kt + 2);
    const u16* bufA = lds + (kt % 3) * 16384;
    short8 af[8], bf[4];
#pragma unroll
    for (int mt = 0; mt < 8; mt++) af[mt] = *(const short8*)&bufA[aoff + mt * 512];
#pragma unroll
    for (int nt = 0; nt < 4; nt++) bf[nt] = *(const short8*)&bufA[boff + nt * 512];
    __builtin_amdgcn_s_setprio(1);
#pragma unroll
    for (int mt = 0; mt < 8; mt++)
#pragma unroll
      for (int nt = 0; nt < 4; nt++)
        acc[mt][nt] = __builtin_amdgcn_mfma_f32_16x16x32_bf16(af[mt], bf[nt], acc[mt][nt], 0, 0, 0);
    __builtin_amdgcn_s_setprio(0);
    if (kt < 22) asm volatile("s_waitcnt vmcnt(4)" ::: "memory");  // tile kt+1 complete
    else         asm volatile("s_waitcnt vmcnt(0)" ::: "memory");  // tail drain
    __builtin_amdgcn_s_barrier();
  }
#undef STAGE_QKV

  if (sel < 2) {
    const float* bias = (sel == 0) ? bq : bk;
    u16* dst = (sel == 0) ? qb : kb;
#pragma unroll
    for (int nt = 0; nt < 4; nt++) {
      int lc = or0 + wvn * 64 + nt * 16 + lm;
      float bb = bias[lc];
#pragma unroll
      for (int mt = 0; mt < 8; mt++) {
        int rowb = m0 + wvm * 128 + mt * 16 + lq * 4;
#pragma unroll
        for (int r = 0; r < 4; r++)
          dst[(size_t)(rowb + r) * HID_ + lc] = f2b(acc[mt][nt][r] + bb);
      }
    }
  } else {
#pragma unroll
    for (int nt = 0; nt < 4; nt++) {
      int lc = or0 + wvn * 64 + nt * 16 + lm;
      int hh = lc >> 6, dv = lc & 63;
      float bb = bv[lc];
#pragma unroll
      for (int mt = 0; mt < 8; mt++) {
        int rowbase = m0 + wvm * 128 + mt * 16 + lq * 4;
        int b = rowbase >> 12, n = rowbase & 4095;
        union { u16 s[4]; uint2 u; } pk;
#pragma unroll
        for (int r = 0; r < 4; r++) pk.s[r] = f2b(acc[mt][nt][r] + bb);
        *(uint2*)(vT + ((size_t)(b * H_ + hh) * DH_ + dv) * N_ + n) = pk.u;
      }
    }
  }
}

// ---------------- global max of k features per (b,h) + diag(k) precompute ----------------
__global__ __launch_bounds__(256) void k_kmax3(
    const u16* __restrict__ kb, const u16* __restrict__ projb,
    unsigned* __restrict__ mbuf, float* __restrict__ diagk) {
  const int bh = blockIdx.y, b = bh / H_, h = bh - b * H_;
  const int n0 = blockIdx.x * 256;
  const int t = threadIdx.x, lane = t & 63, wv = t >> 6;
  const int lm = lane & 15, lq = lane >> 4;
  const u16* kbase = kb + (size_t)(b * N_ + n0 + wv * 64) * HID_ + h * DH_;
  short8 af0[4], af1[4];
#pragma unroll
  for (int mt = 0; mt < 4; mt++) {
    const u16* p = kbase + (size_t)(mt * 16 + lm) * HID_ + lq * 8;
    af0[mt] = *(const short8*)p;
    af1[mt] = *(const short8*)(p + 32);
  }
  // diag(k) = 0.0625 * sum_d k^2 per row — bit-identical to old in-loop computation
#pragma unroll
  for (int mt = 0; mt < 4; mt++) {
    float rs = 0.f;
#pragma unroll
    for (int i = 0; i < 8; i++) { float f = b2f(((const u16*)&af0[mt])[i]); rs += f * f; }
#pragma unroll
    for (int i = 0; i < 8; i++) { float f = b2f(((const u16*)&af1[mt])[i]); rs += f * f; }
    rs += __shfl_xor(rs, 16);
    rs += __shfl_xor(rs, 32);
    if (lq == 0) diagk[(size_t)bh * N_ + n0 + wv * 64 + mt * 16 + lm] = 0.0625f * rs;
  }
  float mx = -3e38f;
  for (int ct = 0; ct < 17; ct++) {
    const u16* pp = projb + (ct * 16 + lm) * DH_ + lq * 8;
    short8 bf0 = *(const short8*)pp;
    short8 bf1 = *(const short8*)(pp + 32);
    bool valid = (ct < 16) || (lm < 10);
#pragma unroll
    for (int mt = 0; mt < 4; mt++) {
      floatx4 a = __builtin_amdgcn_mfma_f32_16x16x32_bf16(af0[mt], bf0, (floatx4){0.f,0.f,0.f,0.f}, 0, 0, 0);
      a = __builtin_amdgcn_mfma_f32_16x16x32_bf16(af1[mt], bf1, a, 0, 0, 0);
      if (valid) {
#pragma unroll
        for (int r = 0; r < 4; r++) mx = fmaxf(mx, a[r]);
      }
    }
  }
#pragma unroll
  for (int o = 1; o < 64; o <<= 1) mx = fmaxf(mx, __shfl_xor(mx, o));
  if (lane == 0) atomicMax(&mbuf[bh], fmap(mx));
}

// ---------------- j-owned k-features + ctx reduction: no atomics, reg accumulator ----------------
// grid: 432 blocks = 48 bh x 9 j-blocks of 32; XCD-swizzled so same-bh blocks share an XCD L2.
__global__ __launch_bounds__(256) void k_ctx4(
    const u16* __restrict__ kb, const u16* __restrict__ vT, const u16* __restrict__ projb,
    const unsigned* __restrict__ mbuf, const float* __restrict__ diagk,
    float* __restrict__ ksum, u16* __restrict__ ctxb) {
  __shared__ u16 kpl[32 * 72];       // [j in tile][n 0..63, pad to 72]
  __shared__ float kred[4][2][16];
  const int orig = blockIdx.x;
  const int lg = (orig & 7) * 54 + (orig >> 3);   // bijective XCD swizzle (432 = 8*54)
  const int bh = lg / 9, jb = lg - bh * 9;
  const int j0 = jb * 32;
  const int b = bh / H_, h = bh - b * H_;
  const int t = threadIdx.x, lane = t & 63, wv = t >> 6;
  const int lm = lane & 15, lq = lane >> 4;
  const float m = funmap(mbuf[bh]);
  const bool vj0 = (j0 + lm) < NB_;
  const bool vj1 = (j0 + 16 + lm) < NB_;
  // proj fragments for this block's 32 j-rows: hoisted for the whole kernel
  short8 bp00, bp01, bp10, bp11;
  {
    const u16* pp = projb + (j0 + lm) * DH_ + lq * 8;
    bp00 = *(const short8*)pp;
    bp01 = *(const short8*)(pp + 32);
    pp += 16 * DH_;
    bp10 = *(const short8*)pp;
    bp11 = *(const short8*)(pp + 32);
  }
  const u16* kbB = kb + (size_t)(b * N_) * HID_ + h * DH_;
  const u16* vTb = vT + ((size_t)bh * DH_ + wv * 16 + lm) * N_;
  const float* dgB = diagk + (size_t)bh * N_;
  floatx4 acc0 = (floatx4){0.f,0.f,0.f,0.f}, acc1 = (floatx4){0.f,0.f,0.f,0.f};
  float kacc0 = 0.f, kacc1 = 0.f;
  // preload tile 0 (k rows + diag)
  const u16* kr0 = kbB + (size_t)(wv * 16 + lm) * HID_ + lq * 8;
  short8 af0 = *(const short8*)kr0;
  short8 af1 = *(const short8*)(kr0 + 32);
  floatx4 dg4 = *(const floatx4*)(dgB + wv * 16 + lq * 4);

  for (int n64 = 0; n64 < N_; n64 += 64) {
    __syncthreads();
    // issue next-tile k/diag prefetch + this-tile v loads (all independent of phase A/B compute)
    const int nn = (n64 + 64 < N_) ? n64 + 64 : 0;
    const u16* krn = kbB + (size_t)(nn + wv * 16 + lm) * HID_ + lq * 8;
    short8 nf0 = *(const short8*)krn;
    short8 nf1 = *(const short8*)(krn + 32);
    floatx4 nd = *(const floatx4*)(dgB + nn + wv * 16 + lq * 4);
    short8 av0 = *(const short8*)(vTb + n64 + lq * 8);
    short8 av1 = *(const short8*)(vTb + n64 + 32 + lq * 8);
    // ---- phase A: features for this wave's 16 n-rows x 32 j ----
    {
      floatx4 a = __builtin_amdgcn_mfma_f32_16x16x32_bf16(af0, bp00, (floatx4){0.f,0.f,0.f,0.f}, 0, 0, 0);
      a = __builtin_amdgcn_mfma_f32_16x16x32_bf16(af1, bp01, a, 0, 0, 0);
      union { u16 s[4]; uint2 u; } pk;
      float kss = 0.f;
#pragma unroll
      for (int r = 0; r < 4; r++) {
        float val = vj0 ? RATIO_ * (__expf(a[r] - dg4[r] - m) + EPS_) : 0.f;
        kss += val;
        pk.s[r] = f2b(val);
      }
      kacc0 += kss;
      *(uint2*)&kpl[lm * 72 + wv * 16 + lq * 4] = pk.u;
      a = __builtin_amdgcn_mfma_f32_16x16x32_bf16(af0, bp10, (floatx4){0.f,0.f,0.f,0.f}, 0, 0, 0);
      a = __builtin_amdgcn_mfma_f32_16x16x32_bf16(af1, bp11, a, 0, 0, 0);
      kss = 0.f;
#pragma unroll
      for (int r = 0; r < 4; r++) {
        float val = vj1 ? RATIO_ * (__expf(a[r] - dg4[r] - m) + EPS_) : 0.f;
        kss += val;
        pk.s[r] = f2b(val);
      }
      kacc1 += kss;
      *(uint2*)&kpl[(16 + lm) * 72 + wv * 16 + lq * 4] = pk.u;
    }
    __syncthreads();
    // ---- phase B: ctx MFMA, wave owns d-rows wv*16..wv*16+15 ----
    {
      short8 bf = *(const short8*)&kpl[lm * 72 + lq * 8];
      acc0 = __builtin_amdgcn_mfma_f32_16x16x32_bf16(av0, bf, acc0, 0, 0, 0);
      bf = *(const short8*)&kpl[(16 + lm) * 72 + lq * 8];
      acc1 = __builtin_amdgcn_mfma_f32_16x16x32_bf16(av0, bf, acc1, 0, 0, 0);
      bf = *(const short8*)&kpl[lm * 72 + 32 + lq * 8];
      acc0 = __builtin_amdgcn_mfma_f32_16x16x32_bf16(av1, bf, acc0, 0, 0, 0);
      bf = *(const short8*)&kpl[(16 + lm) * 72 + 32 + lq * 8];
      acc1 = __builtin_amdgcn_mfma_f32_16x16x32_bf16(av1, bf, acc1, 0, 0, 0);
    }
    af0 = nf0; af1 = nf1; dg4 = nd;
  }
  // ---- ksum: cross-lq shuffle + cross-wave LDS reduce, single plain store ----
  {
    float v0 = kacc0; v0 += __shfl_xor(v0, 16); v0 += __shfl_xor(v0, 32);
    float v1 = kacc1; v1 += __shfl_xor(v1, 16); v1 += __shfl_xor(v1, 32);
    if (lq == 0) { kred[wv][0][lm] = v0; kred[wv][1][lm] = v1; }
  }
  __syncthreads();
  if (t < 32) {
    int jh = t >> 4, l = t & 15;
    ksum[bh * NBP_ + j0 + t] =
        kred[0][jh][l] + kred[1][jh][l] + kred[2][jh][l] + kred[3][jh][l];
  }
  // ---- ctx write: each block owns [64 d][32 j] exclusively — plain bf16 stores ----
  {
    u16* cb = ctxb + ((size_t)bh * DH_ + wv * 16 + lq * 4) * NBP_ + j0 + lm;
#pragma unroll
    for (int r = 0; r < 4; r++) {
      cb[(size_t)r * NBP_] = f2b(acc0[r]);
      cb[(size_t)r * NBP_ + 16] = f2b(acc1[r]);
    }
  }
}

// ---------------- fused q-features + out GEMM (two-pass, low VGPR) ----------------
__global__ __launch_bounds__(256) void k_out3(
    const u16* __restrict__ qb, const u16* __restrict__ projb,
    const u16* __restrict__ ctxb, const float* __restrict__ ksum,
    float* __restrict__ outp) {
  __shared__ u16 qpl[4][16][296];   // per-wave private 16x288 (+8 pad)
  const int bh = blockIdx.y, b = bh / H_, h = bh - b * H_;
  const int n0 = blockIdx.x * 256;
  const int t = threadIdx.x, lane = t & 63, wv = t >> 6;
  const int lm = lane & 15, lq = lane >> 4;
  const u16* qbase = qb + (size_t)(b * N_ + n0 + wv * 64) * HID_ + h * DH_;
  const u16* cb = ctxb + (size_t)bh * DH_ * NBP_;
  const float* ksb = ksum + bh * NBP_;
  float ksv[17];
#pragma unroll
  for (int ct = 0; ct < 17; ct++) ksv[ct] = ksb[ct * 16 + lm];

  for (int mt = 0; mt < 4; mt++) {
    const u16* prow = qbase + (size_t)(mt * 16 + lm) * HID_ + lq * 8;
    short8 af0 = *(const short8*)prow;
    short8 af1 = *(const short8*)(prow + 32);
    float rs = 0.f;
#pragma unroll
    for (int i = 0; i < 8; i++) { float f = b2f(((const u16*)&af0)[i]); rs += f * f; }
#pragma unroll
    for (int i = 0; i < 8; i++) { float f = b2f(((const u16*)&af1)[i]); rs += f * f; }
    rs += __shfl_xor(rs, 16);
    rs += __shfl_xor(rs, 32);
    float dg[4];
#pragma unroll
    for (int r = 0; r < 4; r++) dg[r] = 0.0625f * __shfl(rs, lq * 4 + r);

    // pass 1: row max only (no dd storage)
    float rm[4] = {-3e38f, -3e38f, -3e38f, -3e38f};
#pragma unroll
    for (int ct = 0; ct < 17; ct++) {
      const u16* pp = projb + (ct * 16 + lm) * DH_ + lq * 8;
      short8 bf0 = *(const short8*)pp;
      short8 bf1 = *(const short8*)(pp + 32);
      floatx4 a = __builtin_amdgcn_mfma_f32_16x16x32_bf16(af0, bf0, (floatx4){0.f,0.f,0.f,0.f}, 0, 0, 0);
      a = __builtin_amdgcn_mfma_f32_16x16x32_bf16(af1, bf1, a, 0, 0, 0);
      if ((ct < 16) || (lm < 10)) {
#pragma unroll
        for (int r = 0; r < 4; r++) rm[r] = fmaxf(rm[r], a[r]);
      }
    }
#pragma unroll
    for (int o = 1; o < 16; o <<= 1) {
#pragma unroll
      for (int r = 0; r < 4; r++) rm[r] = fmaxf(rm[r], __shfl_xor(rm[r], o));
    }
    // pass 2: recompute dd, exp, qp -> LDS, d partial
    float dpart[4] = {0.f, 0.f, 0.f, 0.f};
#pragma unroll
    for (int ct = 0; ct < 18; ct++) {
      floatx4 a;
      if (ct < 17) {
        const u16* pp = projb + (ct * 16 + lm) * DH_ + lq * 8;
        short8 bf0 = *(const short8*)pp;
        short8 bf1 = *(const short8*)(pp + 32);
        a = __builtin_amdgcn_mfma_f32_16x16x32_bf16(af0, bf0, (floatx4){0.f,0.f,0.f,0.f}, 0, 0, 0);
        a = __builtin_amdgcn_mfma_f32_16x16x32_bf16(af1, bf1, a, 0, 0, 0);
      } else {
        a = (floatx4){0.f, 0.f, 0.f, 0.f};
      }
      bool valid = (ct < 16) || (ct == 16 && lm < 10);
      float kv = (ct < 17) ? ksv[ct] : 0.f;
#pragma unroll
      for (int r = 0; r < 4; r++) {
        float qpv = valid ? RATIO_ * (__expf(a[r] - dg[r] - rm[r]) + EPS_) : 0.f;
        dpart[r] += qpv * kv;
        qpl[wv][lq * 4 + r][ct * 16 + lm] = f2b(qpv);
      }
    }
#pragma unroll
    for (int o = 1; o < 16; o <<= 1) {
#pragma unroll
      for (int r = 0; r < 4; r++) dpart[r] += __shfl_xor(dpart[r], o);
    }
    float dinv[4];
#pragma unroll
    for (int r = 0; r < 4; r++) dinv[r] = 1.f / dpart[r];

    floatx4 ao[4];
#pragma unroll
    for (int dt = 0; dt < 4; dt++) ao[dt] = (floatx4){0.f, 0.f, 0.f, 0.f};
#pragma unroll
    for (int ks9 = 0; ks9 < 9; ks9++) {
      short8 aq = *(const short8*)&qpl[wv][lm][ks9 * 32 + lq * 8];
#pragma unroll
      for (int dt = 0; dt < 4; dt++) {
        short8 bc = *(const short8*)(cb + (size_t)(dt * 16 + lm) * NBP_ + ks9 * 32 + lq * 8);
        ao[dt] = __builtin_amdgcn_mfma_f32_16x16x32_bf16(aq, bc, ao[dt], 0, 0, 0);
      }
    }
#pragma unroll
    for (int dt = 0; dt < 4; dt++) {
#pragma unroll
      for (int r = 0; r < 4; r++) {
        int n = n0 + wv * 64 + mt * 16 + lq * 4 + r;
        outp[((size_t)(b * N_ + n)) * HID_ + h * DH_ + dt * 16 + lm] = ao[dt][r] * dinv[r];
      }
    }
  }
}

extern "C" void kernel_launch(void* const* d_in, const int* in_sizes, int n_in,
                              void* d_out, int out_size, void* d_ws, size_t ws_size,
                              hipStream_t stream) {
  (void)in_sizes; (void)n_in; (void)out_size; (void)ws_size;
  const float* hs   = (const float*)d_in[0];
  const float* Wq   = (const float*)d_in[1];
  const float* bq   = (const float*)d_in[2];
  const float* Wk   = (const float*)d_in[3];
  const float* bk   = (const float*)d_in[4];
  const float* Wv   = (const float*)d_in[5];
  const float* bv   = (const float*)d_in[6];
  const float* proj = (const float*)d_in[7];

  char* w = (char*)d_ws;
  u16* hsb   = (u16*)w;  w += (size_t)16384 * 768 * 2;
  u16* wb3   = (u16*)w;  w += (size_t)3 * 768 * 768 * 2;
  u16* projb = (u16*)w;  w += (size_t)NBP_ * 64 * 2;
  u16* qb    = (u16*)w;  w += (size_t)16384 * 768 * 2;
  u16* kb    = (u16*)w;  w += (size_t)16384 * 768 * 2;
  u16* vT    = (u16*)w;  w += (size_t)48 * DH_ * N_ * 2;   // [bh][dv][n]
  float* ksum  = (float*)w; w += (size_t)48 * NBP_ * 4;
  float* diagk = (float*)w; w += (size_t)48 * N_ * 4;      // [bh][n] = 0.0625*sum k^2
  u16* ctxTb = (u16*)w;  w += (size_t)48 * DH_ * NBP_ * 2;
  unsigned* mbuf = (unsigned*)w;

  hipLaunchKernelGGL(k_prep, dim3(14089), dim3(256), 0, stream,
                     (const float4*)hs, (const float4*)Wq, (const float4*)Wk, (const float4*)Wv,
                     proj, (uint2*)hsb, (uint2*)wb3, projb, mbuf);
  hipLaunchKernelGGL(k_qkv2, dim3(576), dim3(512), 0, stream, hsb, wb3, bq, bk, bv, qb, kb, vT);
  hipLaunchKernelGGL(k_kmax3, dim3(16, 48), dim3(256), 0, stream, kb, projb, mbuf, diagk);
  hipLaunchKernelGGL(k_ctx4, dim3(432), dim3(256), 0, stream, kb, vT, projb, mbuf, diagk, ksum, ctxTb);
  hipLaunchKernelGGL(k_out3, dim3(16, 48), dim3(256), 0, stream, qb, projb, ctxTb, ksum, (float*)d_out);
}